// Round 9
// baseline (455.268 us; speedup 1.0000x reference)
//
#include <hip/hip_runtime.h>
#include <math.h>

// ---- problem constants (match reference) ----
static constexpr int NYI  = 256;
static constexpr int PMLW = 20;
static constexpr int NY   = 296, NX = 296;
static constexpr int NCELL = NY * NX;
static constexpr int NS   = 2;
static constexpr int NSRC = 8;
static constexpr int NREC = 64;
static constexpr int NT   = 64;
static constexpr float DXF = 4.0f;
static constexpr float DTF = 5e-4f;
static constexpr float FC1 = 9.0f / 8.0f;
static constexpr float FC2 = -1.0f / 24.0f;
static constexpr float INV_DX = 1.0f / DXF;

// ---- decomposition: 8x8 tiles of 37x37 (128 blocks; R4 proved 256 is worse).
//      QUAD threads (R6/R7: halves VALU time).
//      R9: bank-phase alignment via PADDED lane strides, ownership = R6/R7's
//      proven causal split (early rows 3..33 x cols 4..31 ONLY -- R8's extension
//      to cols 32,33 read stale boundary vel and raced boundary-vel taps):
//        early: 8 lanes/row, lane7 idle, quads 1..7  -> conflict-free reads
//        late full ring rows: 16 lanes/row, quads 0..9 + 6 idle -> conflict-free
//        late strips: 4 lanes/row {q0,q8,q9,idle} -> <=2-way (free, m136)
//      Ring publish stays inside the stress phases as dense 16B stores.
static constexpr int TB = 8, TS = 37;
static constexpr int NBLK = TB * TB * NS;      // 128
static constexpr int NTHR = 512;
static constexpr int SVW = 44, VROWS = 41;     // vel region 41x41, padded stride 44
static constexpr int SSW = 48, SROWS = 45;     // stress region 45x45, padded stride 48
// vel quads: 41 rows x 11 quads = 451.  interior (rows 4..37, quads 1..8) = 272.
static constexpr int NVINT = 272, NVTOT = 451;
static constexpr int SFRAME = 656;             // 45^2 - 37^2 frame cells
// stress EARLY: tid 0..247 -> rows 3..33 (tid>>3), lanes 0..6 = quads 1..7, lane7 idle
static constexpr int NSE = 248;
// stress LATE: tid 256..475 -> [0,96) full ring rows {0,1,2,34,35,36} x 16 lanes;
//              [96,220) strips rows 3..33 x 4 lanes {quad0, quad8, quad9, idle}
static constexpr int LBASE = 256, LSPAN = 220;

// ---- global ws layout (floats): parity-double-buffered stress + flags + vmax slots ----
// NO memset needed: flags poison (0xAAAAAAAA) reads as negative int = "not ready";
// vmax slots poison has sign bit set = "not written" (real values are positive floats).
static constexpr int GSLOT   = 3 * NS * NCELL;
static constexpr int FLG_OFF = 2 * GSLOT;

typedef float f32x4 __attribute__((ext_vector_type(4)));

__device__ __forceinline__ float cohload(const float* p) {
    return __hip_atomic_load(p, __ATOMIC_RELAXED, __HIP_MEMORY_SCOPE_AGENT);
}
__device__ __forceinline__ void cohstore(float* p, float v) {
    __hip_atomic_store(p, v, __ATOMIC_RELAXED, __HIP_MEMORY_SCOPE_AGENT);
}
// dense agent-coherent 16B store (dword-aligned; gfx9 global ops allow it)
__device__ __forceinline__ void coh_store4(float* p, f32x4 v) {
    asm volatile("global_store_dwordx4 %0, %1, off sc1" :: "v"(p), "v"(v) : "memory");
}

// 8-float window load as 2 aligned float4s into a statically-indexed register array
// (function, not macro: a macro parameter named w would capture the .w member token)
__device__ __forceinline__ void ld8(float* __restrict__ dst,
                                    const float* __restrict__ arr, int idx) {
    float4 A_ = *(const float4*)&arr[idx];
    float4 B_ = *(const float4*)&arr[idx + 4];
    dst[0] = A_.x; dst[1] = A_.y; dst[2] = A_.z; dst[3] = A_.w;
    dst[4] = B_.x; dst[5] = B_.y; dst[6] = B_.z; dst[7] = B_.w;
}

__global__ __launch_bounds__(NTHR, 1)
void elastic_fused(const float* __restrict__ lamb, const float* __restrict__ mu,
                   const float* __restrict__ buoy, const float* __restrict__ amps,
                   const int* __restrict__ src_loc, const int* __restrict__ rec_loc,
                   float* __restrict__ out, float* __restrict__ ws)
{
    __shared__ __align__(16) float sSyy[SROWS * SSW];
    __shared__ __align__(16) float sSxy[SROWS * SSW];
    __shared__ __align__(16) float sSxx[SROWS * SSW];
    __shared__ __align__(16) float sVy[VROWS * SVW];
    __shared__ __align__(16) float sVx[VROWS * SVW];
    __shared__ float sAmp[NSRC * NT];    // (first reused as uint sred[NBLK] for vmax)
    __shared__ float wmax[NTHR / 64];
    __shared__ int   rcnt;
    __shared__ short rl_r[NREC];
    __shared__ int   rl_pos[NREC];

    int* flags = (int*)(ws + FLG_OFF);
    unsigned* gvm = (unsigned*)(flags + NBLK);
    float* gstr = ws;

    const int tid  = threadIdx.x;
    const int shot = blockIdx.x & 1;
    const int tb   = blockIdx.x >> 1;
    const int bty  = tb >> 3, btx = tb & 7;
    const int gy0  = bty * TS, gx0 = btx * TS;
    const int myBlk = blockIdx.x;

    // poll thread -> one spatial neighbor (same shot); frame touches corners -> all 8
    int myNbr = -1;
    if (tid < 8) {
        int idx = tid < 4 ? tid : tid + 1;
        int dy = idx / 3 - 1, dx = idx % 3 - 1;
        int nty = bty + dy, ntx = btx + dx;
        if (nty >= 0 && nty < TB && ntx >= 0 && ntx < TB)
            myNbr = ((nty * TB + ntx) << 1) | shot;
    }

    // ---- zero LDS fields (incl. pad cols; global stress bufs need no init: t0 frame=0) ----
    for (int i = tid; i < SROWS * SSW; i += NTHR) { sSyy[i] = 0.0f; sSxy[i] = 0.0f; sSxx[i] = 0.0f; }
    for (int i = tid; i < VROWS * SVW; i += NTHR) { sVy[i] = 0.0f; sVx[i] = 0.0f; }
    if (tid == 0) rcnt = 0;

    // ---- distributed vmax (bit-identical: uint-max == float-max for positives) ----
    {
        int i = myBlk * NTHR + tid;     // 128 * 512 = 65536 = NYI*NYI exactly
        float v = (lamb[i] + 2.0f * mu[i]) * buoy[i];
        #pragma unroll
        for (int off = 32; off > 0; off >>= 1)
            v = fmaxf(v, __shfl_down(v, off));
        if ((tid & 63) == 0) wmax[tid >> 6] = v;
    }

    // ---- vel quad mapping (phase-packed: interior quads first; 8 quads/row) ----
    const bool vact = tid < NVTOT;
    const bool vint = tid < NVINT;
    int vrow = 0, vq = 0;
    if (vint) { vrow = 4 + tid / 8; vq = 1 + (tid & 7); }
    else if (vact) {
        int j = tid - NVINT;
        if (j < 44)      { vrow = j / 11; vq = j % 11; }
        else if (j < 77) { int k = j - 44; vrow = 38 + k / 11; vq = k % 11; }
        else             { int k = j - 77; vrow = 4 + k / 3; int c = k % 3;
                           vq = (c == 0) ? 0 : (c == 1 ? 9 : 10); }
    }
    const int c0v = 4 * vq;
    const int gyv = gy0 - 2 + vrow;

    // hoist source coords
    int sly[NSRC], slx[NSRC];
    #pragma unroll
    for (int s = 0; s < NSRC; ++s) {
        sly[s] = src_loc[(shot * NSRC + s) * 2 + 0] + PMLW;
        slx[s] = src_loc[(shot * NSRC + s) * 2 + 1] + PMLW;
    }

    int vdm = 0, smk4 = 0;
    float buo[4];
    #pragma unroll
    for (int m = 0; m < 4; ++m) {
        int vx_ = c0v + m;
        int gx = gx0 - 2 + vx_;
        bool ing = vact && vx_ <= 40 && gyv >= 0 && gyv < NY && gx >= 0 && gx < NX;
        if (ing) vdm |= 1 << m;
        float b = 0.0f;
        if (ing) {
            int iy = min(max(gyv - PMLW, 0), NYI - 1);
            int ix = min(max(gx - PMLW, 0), NYI - 1);
            b = buoy[iy * NYI + ix];
        }
        buo[m] = b;
        #pragma unroll
        for (int s = 0; s < NSRC; ++s)
            if (ing && sly[s] == gyv && slx[s] == gx) smk4 |= 1 << (m * 8 + s);
    }

    // ---- EARLY stress: rows 3..33, quads 1..7, 8-lane row stride (lane7 idle).
    //      Causality (proven in R6/R7): cells rows 3..33 x cols 4..31 only --
    //      vel taps rows 2..35, cols 3..33 all interior; boundary-vel stress taps
    //      (rows <=2 / >=34, cols <=2 / >=32) disjoint from writes. ----
    const bool sE = (tid < NSE) && ((tid & 7) != 7);
    const int trowE = sE ? 3 + (tid >> 3) : 3;
    const int tqE   = sE ? 1 + (tid & 7) : 1;
    const int q0E   = 4 * tqE;
    const int wmE   = sE ? 0xF : 0;
    const int pbE   = (sE && (trowE == 3 || trowE == 33)) ? 0xF : 0;   // ring rows only
    const int gidxE = (gy0 + trowE) * NX + gx0 + q0E;
    float lamE[4], muvE[4], l2mE[4];
    #pragma unroll
    for (int m = 0; m < 4; ++m) {
        float la = 0.0f, mm_ = 0.0f;
        if ((wmE >> m) & 1) {
            int iy = min(max(gy0 + trowE - PMLW, 0), NYI - 1);
            int ix = min(max(gx0 + q0E + m - PMLW, 0), NYI - 1);
            la = lamb[iy * NYI + ix];
            mm_ = mu[iy * NYI + ix];
        }
        lamE[m] = la; muvE[m] = mm_; l2mE[m] = la + 2.0f * mm_;
    }

    // ---- LATE stress: ring complement of EARLY (501 cells):
    //      [0,96): full rows {0,1,2,34,35,36}, 16 lanes/row, quads 0..9 active
    //      [96,220): strip rows 3..33, 4 lanes/row {quad0, quad8(cells32..35), quad9} ----
    const int jL = tid - LBASE;
    bool sL = false; int trowL = 0, tqL = 0, wmL = 0, pbL = 0;
    if (jL >= 0 && jL < LSPAN) {
        if (jL < 96) {
            int r6 = jL >> 4, lane = jL & 15;
            if (lane <= 9) {
                sL = true; trowL = r6 < 3 ? r6 : 31 + r6; tqL = lane;
                wmL = lane < 9 ? 0xF : 0x1;      // quad9: cell 36 only
                pbL = wmL;                        // full ring rows: everything is ring
            }
        } else {
            int k = jL - 96; int r = k >> 2, c = k & 3;
            if (c < 3) {
                sL = true; trowL = 3 + r;
                if (c == 0)      { tqL = 0; wmL = 0xF; pbL = 0xF; }            // cells 0..3 (ring cols)
                else if (c == 1) { tqL = 8; wmL = 0xF;                          // cells 32..35
                                   pbL = (trowL == 3 || trowL == 33) ? 0xF : 0xE; } // 32 ring only on ring rows
                else             { tqL = 9; wmL = 0x1; pbL = 0x1; }            // cell 36 (ring col)
            }
        }
    }
    const int q0L   = 4 * tqL;
    const int gidxL = (gy0 + trowL) * NX + gx0 + q0L;
    float lamL[4], muvL[4], l2mL[4];
    #pragma unroll
    for (int m = 0; m < 4; ++m) {
        float la = 0.0f, mm_ = 0.0f;
        if ((wmL >> m) & 1) {
            int iy = min(max(gy0 + trowL - PMLW, 0), NYI - 1);
            int ix = min(max(gx0 + q0L + m - PMLW, 0), NYI - 1);
            la = lamb[iy * NYI + ix];
            mm_ = mu[iy * NYI + ix];
        }
        lamL[m] = la; muvL[m] = mm_; l2mL[m] = la + 2.0f * mm_;
    }

    // ---- frame-slot geometry (2 slots; stride 48) ----
    bool fval[2], fin[2];
    int  flidx[2], fgi[2];
    #pragma unroll
    for (int k = 0; k < 2; ++k) {
        int ff = tid + NTHR * k;
        fval[k] = ff < SFRAME;
        int fy = 0, fx = 0;
        if (fval[k]) {
            if (ff < 4 * SROWS)      { fy = ff / SROWS; fx = ff - fy * SROWS; }
            else if (ff < 8 * SROWS) { int r = ff - 4 * SROWS; fy = 41 + r / SROWS; fx = r % SROWS; }
            else {
                int r = ff - 8 * SROWS;
                if (r < 37 * 4) { fy = 4 + (r >> 2); fx = r & 3; }
                else { r -= 37 * 4; fy = 4 + (r >> 2); fx = 41 + (r & 3); }
            }
        }
        int gy = gy0 - 4 + fy, gx = gx0 - 4 + fx;
        fin[k]   = fval[k] && gy >= 0 && gy < NY && gx >= 0 && gx < NX;
        flidx[k] = fy * SSW + fx;
        fgi[k]   = fin[k] ? (gy * NX + gx) : 0;
    }

    __syncthreads();   // wmax partials + LDS zeros + rcnt=0 visible

    // ---- grid all-reduce of vmax via poison-safe per-block slots ----
    if (tid == 0) {
        float v = wmax[0];
        #pragma unroll
        for (int w = 1; w < NTHR / 64; ++w) v = fmaxf(v, wmax[w]);
        __hip_atomic_store(&gvm[myBlk], __float_as_uint(v), __ATOMIC_RELAXED,
                           __HIP_MEMORY_SCOPE_AGENT);
    }
    unsigned* sred = (unsigned*)sAmp;
    if (tid < NBLK) {
        unsigned v;
        for (;;) {
            v = __hip_atomic_load(&gvm[tid], __ATOMIC_RELAXED, __HIP_MEMORY_SCOPE_AGENT);
            if (!(v & 0x80000000u)) break;
            __builtin_amdgcn_s_sleep(1);
        }
        sred[tid] = v;
    }
    __syncthreads();
    if (tid == 0) {
        unsigned mb = sred[0];
        for (int i = 1; i < NBLK; ++i) mb = mb > sred[i] ? mb : sred[i];
        wmax[0] = __uint_as_float(mb);
    }
    __syncthreads();

    // ---- per-thread CPML profile tables (registers; no LDS table reads in loop) ----
    const float max_vel = sqrtf(wmax[0]);
    const float sig_max = 3.0f * max_vel * logf(1000.0f) / (2.0f * PMLW * DXF);
    auto prof = [&](int g) -> float {
        float fi = (float)g;
        float d1 = fmaxf((float)PMLW - fi, 0.0f);
        float d2 = fmaxf(fi - (float)(NY - 1 - PMLW), 0.0f);
        float dd = fmaxf(d1, d2) * (1.0f / (float)PMLW);
        return expf(-(sig_max * dd * dd) * DTF);
    };
    const float byv = prof(gyv), ayv = byv - 1.0f;
    const float bysE = prof(gy0 + trowE), aysE = bysE - 1.0f;
    const float bysL = prof(gy0 + trowL), aysL = bysL - 1.0f;
    float bxv[4], axv[4], bxsE[4], axsE[4], bxsL[4], axsL[4];
    #pragma unroll
    for (int m = 0; m < 4; ++m) {
        bxv[m]  = prof(gx0 - 2 + c0v + m); axv[m]  = bxv[m]  - 1.0f;
        bxsE[m] = prof(gx0 + q0E + m);     axsE[m] = bxsE[m] - 1.0f;
        bxsL[m] = prof(gx0 + q0L + m);     axsL[m] = bxsL[m] - 1.0f;
    }

    if (tid < NREC) {
        int r = tid;
        int ry = rec_loc[(shot * NREC + r) * 2 + 0] + PMLW;
        int rx = rec_loc[(shot * NREC + r) * 2 + 1] + PMLW;
        if (ry >= gy0 && ry < gy0 + TS && rx >= gx0 && rx < gx0 + TS) {
            int p = atomicAdd(&rcnt, 1);
            rl_r[p]   = (short)r;
            rl_pos[p] = (ry - gy0 + 2) * SVW + (rx - gx0 + 2);
        }
    }
    __syncthreads();   // sred reads done before sAmp overwrite
    for (int i = tid; i < NSRC * NT; i += NTHR)
        sAmp[i] = amps[shot * NSRC * NT + i];
    __syncthreads();

    // ---- CPML memory state (registers, statically indexed) ----
    float msyyy[4] = {0,0,0,0}, msxyx[4] = {0,0,0,0};
    float msxyy[4] = {0,0,0,0}, msxxx[4] = {0,0,0,0};
    float mvyyE[4] = {0,0,0,0}, mvxxE[4] = {0,0,0,0}, mvyxE[4] = {0,0,0,0}, mvxyE[4] = {0,0,0,0};
    float mvyyL[4] = {0,0,0,0}, mvxxL[4] = {0,0,0,0}, mvyxL[4] = {0,0,0,0}, mvxyL[4] = {0,0,0,0};

    // velocity quad: 8-float windows, expression-identical per-cell math
    auto vel_quad = [&](int t) {
        const int sb = vrow * SSW + c0v;     // window row 0 = S-row vy_ (taps rows vy_..vy_+3)
        float r0[8], r1[8], r2[8], r3[8];
        float dsyy_y[4], dsxy_x[4], dsxy_y[4], dsxx_x[4];
        ld8(r0, sSyy, sb); ld8(r1, sSyy, sb + SSW);
        ld8(r2, sSyy, sb + 2 * SSW); ld8(r3, sSyy, sb + 3 * SSW);
        #pragma unroll
        for (int m = 0; m < 4; ++m)
            dsyy_y[m] = (FC1 * (r2[m+2] - r1[m+2]) + FC2 * (r3[m+2] - r0[m+2])) * INV_DX;
        ld8(r0, sSxy, sb); ld8(r1, sSxy, sb + SSW);
        ld8(r2, sSxy, sb + 2 * SSW); ld8(r3, sSxy, sb + 3 * SSW);
        #pragma unroll
        for (int m = 0; m < 4; ++m) {
            dsxy_y[m] = (FC1 * (r2[m+2] - r1[m+2]) + FC2 * (r3[m+2] - r0[m+2])) * INV_DX;
            dsxy_x[m] = (FC1 * (r2[m+2] - r2[m+1]) + FC2 * (r2[m+3] - r2[m])) * INV_DX;
        }
        ld8(r0, sSxx, sb + 2 * SSW);         // x-deriv needs only the center row
        #pragma unroll
        for (int m = 0; m < 4; ++m)
            dsxx_x[m] = (FC1 * (r0[m+2] - r0[m+1]) + FC2 * (r0[m+3] - r0[m])) * INV_DX;

        const int vb = vrow * SVW + c0v;
        float4 oy4 = *(const float4*)&sVy[vb];
        float4 ox4 = *(const float4*)&sVx[vb];
        float ovy[4] = {oy4.x, oy4.y, oy4.z, oy4.w};
        float ovx[4] = {ox4.x, ox4.y, ox4.z, ox4.w};
        float nvy[4], nvx[4];
        #pragma unroll
        for (int m = 0; m < 4; ++m) {
            float mm;
            mm = byv * msyyy[m] + ayv * dsyy_y[m];      msyyy[m] = mm; float dy1 = dsyy_y[m] + mm;
            mm = bxv[m] * msxyx[m] + axv[m] * dsxy_x[m]; msxyx[m] = mm; float dx1 = dsxy_x[m] + mm;
            mm = byv * msxyy[m] + ayv * dsxy_y[m];      msxyy[m] = mm; float dy2 = dsxy_y[m] + mm;
            mm = bxv[m] * msxxx[m] + axv[m] * dsxx_x[m]; msxxx[m] = mm; float dx2 = dsxx_x[m] + mm;
            nvy[m] = ovy[m] + DTF * buo[m] * (dy1 + dx1);
            nvx[m] = ovx[m] + DTF * buo[m] * (dy2 + dx2);
        }
        if (smk4) {
            #pragma unroll
            for (int m = 0; m < 4; ++m) {
                #pragma unroll
                for (int s = 0; s < NSRC; ++s)
                    if ((smk4 >> (m * 8 + s)) & 1) nvy[m] += DTF * buo[m] * sAmp[s * NT + t];
            }
        }
        if (vdm == 0xF) {
            *(float4*)&sVy[vb] = make_float4(nvy[0], nvy[1], nvy[2], nvy[3]);
            *(float4*)&sVx[vb] = make_float4(nvx[0], nvx[1], nvx[2], nvx[3]);
        } else {
            #pragma unroll
            for (int m = 0; m < 4; ++m)
                if ((vdm >> m) & 1) { sVy[vb + m] = nvy[m]; sVx[vb + m] = nvx[m]; }
        }
    };

    // EARLY stress body: rows 3..33 x quads 1..7; ring rows publish inline (dense 16B)
    auto stress_early = [&](float* gsw) {
        const int vb = (trowE + 1) * SVW + q0E;
        float y0[8], y1[8], y2[8], y3[8];
        float dvy_y[4], dvy_x[4], dvx_y[4], dvx_x[4];
        ld8(y0, sVy, vb); ld8(y1, sVy, vb + SVW);
        ld8(y2, sVy, vb + 2 * SVW); ld8(y3, sVy, vb + 3 * SVW);
        #pragma unroll
        for (int m = 0; m < 4; ++m) {
            dvy_y[m] = (FC1 * (y2[m+2] - y1[m+2]) + FC2 * (y3[m+2] - y0[m+2])) * INV_DX;
            dvy_x[m] = (FC1 * (y1[m+3] - y1[m+2]) + FC2 * (y1[m+4] - y1[m+1])) * INV_DX;
        }
        ld8(y0, sVx, vb); ld8(y1, sVx, vb + SVW);
        ld8(y2, sVx, vb + 2 * SVW); ld8(y3, sVx, vb + 3 * SVW);
        #pragma unroll
        for (int m = 0; m < 4; ++m) {
            dvx_x[m] = (FC1 * (y1[m+3] - y1[m+2]) + FC2 * (y1[m+4] - y1[m+1])) * INV_DX;
            dvx_y[m] = (FC1 * (y2[m+2] - y1[m+2]) + FC2 * (y3[m+2] - y0[m+2])) * INV_DX;
        }
        const int sb = (trowE + 4) * SSW + q0E + 4;
        float4 a4 = *(const float4*)&sSyy[sb];
        float4 b4 = *(const float4*)&sSxy[sb];
        float4 c4 = *(const float4*)&sSxx[sb];
        float os0[4] = {a4.x, a4.y, a4.z, a4.w};
        float os1[4] = {b4.x, b4.y, b4.z, b4.w};
        float os2[4] = {c4.x, c4.y, c4.z, c4.w};
        float nsyy[4], nsxy[4], nsxx[4];
        #pragma unroll
        for (int m = 0; m < 4; ++m) {
            float mm;
            mm = bysE * mvyyE[m] + aysE * dvy_y[m];        mvyyE[m] = mm; float fy = dvy_y[m] + mm;
            mm = bxsE[m] * mvxxE[m] + axsE[m] * dvx_x[m];  mvxxE[m] = mm; float fx = dvx_x[m] + mm;
            nsyy[m] = os0[m] + DTF * (l2mE[m] * fy + lamE[m] * fx);
            nsxx[m] = os2[m] + DTF * (lamE[m] * fy + l2mE[m] * fx);
            mm = bxsE[m] * mvyxE[m] + axsE[m] * dvy_x[m];  mvyxE[m] = mm; float gx_ = dvy_x[m] + mm;
            mm = bysE * mvxyE[m] + aysE * dvx_y[m];        mvxyE[m] = mm; float gy_ = dvx_y[m] + mm;
            nsxy[m] = os1[m] + DTF * muvE[m] * (gx_ + gy_);
        }
        *(float4*)&sSyy[sb] = make_float4(nsyy[0], nsyy[1], nsyy[2], nsyy[3]);
        *(float4*)&sSxy[sb] = make_float4(nsxy[0], nsxy[1], nsxy[2], nsxy[3]);
        *(float4*)&sSxx[sb] = make_float4(nsxx[0], nsxx[1], nsxx[2], nsxx[3]);
        if (pbE == 0xF) {
            coh_store4(&gsw[(0 * NS + shot) * NCELL + gidxE], (f32x4){nsyy[0], nsyy[1], nsyy[2], nsyy[3]});
            coh_store4(&gsw[(1 * NS + shot) * NCELL + gidxE], (f32x4){nsxy[0], nsxy[1], nsxy[2], nsxy[3]});
            coh_store4(&gsw[(2 * NS + shot) * NCELL + gidxE], (f32x4){nsxx[0], nsxx[1], nsxx[2], nsxx[3]});
        }
    };

    // LATE stress body: ring complement; publishes per pbL (dense 16B when full)
    auto stress_late = [&](float* gsw) {
        const int vb = (trowL + 1) * SVW + q0L;
        float y0[8], y1[8], y2[8], y3[8];
        float dvy_y[4], dvy_x[4], dvx_y[4], dvx_x[4];
        ld8(y0, sVy, vb); ld8(y1, sVy, vb + SVW);
        ld8(y2, sVy, vb + 2 * SVW); ld8(y3, sVy, vb + 3 * SVW);
        #pragma unroll
        for (int m = 0; m < 4; ++m) {
            dvy_y[m] = (FC1 * (y2[m+2] - y1[m+2]) + FC2 * (y3[m+2] - y0[m+2])) * INV_DX;
            dvy_x[m] = (FC1 * (y1[m+3] - y1[m+2]) + FC2 * (y1[m+4] - y1[m+1])) * INV_DX;
        }
        ld8(y0, sVx, vb); ld8(y1, sVx, vb + SVW);
        ld8(y2, sVx, vb + 2 * SVW); ld8(y3, sVx, vb + 3 * SVW);
        #pragma unroll
        for (int m = 0; m < 4; ++m) {
            dvx_x[m] = (FC1 * (y1[m+3] - y1[m+2]) + FC2 * (y1[m+4] - y1[m+1])) * INV_DX;
            dvx_y[m] = (FC1 * (y2[m+2] - y1[m+2]) + FC2 * (y3[m+2] - y0[m+2])) * INV_DX;
        }
        const int sb = (trowL + 4) * SSW + q0L + 4;
        float4 a4 = *(const float4*)&sSyy[sb];
        float4 b4 = *(const float4*)&sSxy[sb];
        float4 c4 = *(const float4*)&sSxx[sb];
        float os0[4] = {a4.x, a4.y, a4.z, a4.w};
        float os1[4] = {b4.x, b4.y, b4.z, b4.w};
        float os2[4] = {c4.x, c4.y, c4.z, c4.w};
        float nsyy[4], nsxy[4], nsxx[4];
        #pragma unroll
        for (int m = 0; m < 4; ++m) {
            float mm;
            mm = bysL * mvyyL[m] + aysL * dvy_y[m];        mvyyL[m] = mm; float fy = dvy_y[m] + mm;
            mm = bxsL[m] * mvxxL[m] + axsL[m] * dvx_x[m];  mvxxL[m] = mm; float fx = dvx_x[m] + mm;
            nsyy[m] = os0[m] + DTF * (l2mL[m] * fy + lamL[m] * fx);
            nsxx[m] = os2[m] + DTF * (lamL[m] * fy + l2mL[m] * fx);
            mm = bxsL[m] * mvyxL[m] + axsL[m] * dvy_x[m];  mvyxL[m] = mm; float gx_ = dvy_x[m] + mm;
            mm = bysL * mvxyL[m] + aysL * dvx_y[m];        mvxyL[m] = mm; float gy_ = dvx_y[m] + mm;
            nsxy[m] = os1[m] + DTF * muvL[m] * (gx_ + gy_);
        }
        if (wmL == 0xF) {
            *(float4*)&sSyy[sb] = make_float4(nsyy[0], nsyy[1], nsyy[2], nsyy[3]);
            *(float4*)&sSxy[sb] = make_float4(nsxy[0], nsxy[1], nsxy[2], nsxy[3]);
            *(float4*)&sSxx[sb] = make_float4(nsxx[0], nsxx[1], nsxx[2], nsxx[3]);
        } else {
            #pragma unroll
            for (int m = 0; m < 4; ++m)
                if ((wmL >> m) & 1) { sSyy[sb+m] = nsyy[m]; sSxy[sb+m] = nsxy[m]; sSxx[sb+m] = nsxx[m]; }
        }
        if (pbL == 0xF) {
            coh_store4(&gsw[(0 * NS + shot) * NCELL + gidxL], (f32x4){nsyy[0], nsyy[1], nsyy[2], nsyy[3]});
            coh_store4(&gsw[(1 * NS + shot) * NCELL + gidxL], (f32x4){nsxy[0], nsxy[1], nsxy[2], nsxy[3]});
            coh_store4(&gsw[(2 * NS + shot) * NCELL + gidxL], (f32x4){nsxx[0], nsxx[1], nsxx[2], nsxx[3]});
        } else if (pbL) {
            #pragma unroll
            for (int m = 0; m < 4; ++m)
                if ((pbL >> m) & 1) {
                    cohstore(&gsw[(0 * NS + shot) * NCELL + gidxL + m], nsyy[m]);
                    cohstore(&gsw[(1 * NS + shot) * NCELL + gidxL + m], nsxy[m]);
                    cohstore(&gsw[(2 * NS + shot) * NCELL + gidxL + m], nsxx[m]);
                }
        }
    };

    // ========== time loop:
    // [vel-int | poll] B1 [frame loads; EARLY stress (+ring pub) overlaps; frame->LDS]
    // B2 [vel-bnd] B3 [recv; LATE stress (+ring pub)] vmcnt(0) B4 [flag]. ==========
    for (int t = 0; t < NT; ++t) {
        const float* gsr = gstr + ((t + 1) & 1) * GSLOT;
        float*       gsw = gstr + (t & 1) * GSLOT;

        // interior velocity (waves 0..4): no frame dependency
        if (vint) vel_quad(t);

        if (t > 0 && myNbr >= 0) {
            while (__hip_atomic_load(&flags[myNbr], __ATOMIC_RELAXED,
                                     __HIP_MEMORY_SCOPE_AGENT) < t)
                __builtin_amdgcn_s_sleep(1);
        }
        __syncthreads();   // B1

        // issue frame loads; early stress overlaps their latency
        float fr0[3], fr1[3];
        #pragma unroll
        for (int f = 0; f < 3; ++f) {
            fr0[f] = (t > 0 && fin[0]) ? cohload(&gsr[(f * NS + shot) * NCELL + fgi[0]]) : 0.0f;
            fr1[f] = (t > 0 && fin[1]) ? cohload(&gsr[(f * NS + shot) * NCELL + fgi[1]]) : 0.0f;
        }

        if (sE) stress_early(gsw);

        if (fval[0]) { sSyy[flidx[0]] = fr0[0]; sSxy[flidx[0]] = fr0[1]; sSxx[flidx[0]] = fr0[2]; }
        if (fval[1]) { sSyy[flidx[1]] = fr1[0]; sSxy[flidx[1]] = fr1[1]; sSxx[flidx[1]] = fr1[2]; }
        __syncthreads();   // B2

        // boundary velocity (needs frame)
        if (vact && !vint) vel_quad(t);
        __syncthreads();   // B3

        if (tid < rcnt)
            out[(shot * NREC + rl_r[tid]) * NT + t] = sVy[rl_pos[tid]];

        if (sL) stress_late(gsw);

        // all threads drain their own vmem (covers inline-asm ring stores, which the
        // compiler's pre-barrier waitcnt does not track) before the flag handshake
        asm volatile("s_waitcnt vmcnt(0)" ::: "memory");
        __syncthreads();   // B4
        if (tid == 0 && t < NT - 1)
            __hip_atomic_store(&flags[myBlk], t + 1, __ATOMIC_RELAXED,
                               __HIP_MEMORY_SCOPE_AGENT);
    }
}

extern "C" void kernel_launch(void* const* d_in, const int* in_sizes, int n_in,
                              void* d_out, int out_size, void* d_ws, size_t ws_size,
                              hipStream_t stream) {
    const float* lamb    = (const float*)d_in[0];
    const float* mu      = (const float*)d_in[1];
    const float* buoy    = (const float*)d_in[2];
    const float* amps    = (const float*)d_in[3];
    const int*   src_loc = (const int*)d_in[4];
    const int*   rec_loc = (const int*)d_in[5];
    float* ws  = (float*)d_ws;
    float* out = (float*)d_out;

    // No memset needed: flags/vmax-slots are poison-tolerant (see ws layout comment).
    elastic_fused<<<NBLK, NTHR, 0, stream>>>(lamb, mu, buoy, amps, src_loc, rec_loc, out, ws);
}

// Round 10
// 357.339 us; speedup vs baseline: 1.2741x; 1.2741x over previous
//
#include <hip/hip_runtime.h>
#include <math.h>

// ---- problem constants (match reference) ----
static constexpr int NYI  = 256;
static constexpr int PMLW = 20;
static constexpr int NY   = 296, NX = 296;
static constexpr int NCELL = NY * NX;
static constexpr int NS   = 2;
static constexpr int NSRC = 8;
static constexpr int NREC = 64;
static constexpr int NT   = 64;
static constexpr float DXF = 4.0f;
static constexpr float DTF = 5e-4f;
static constexpr float FC1 = 9.0f / 8.0f;
static constexpr float FC2 = -1.0f / 24.0f;
static constexpr float INV_DX = 1.0f / DXF;

// ---- decomposition: 8x8 tiles of 37x37 (128 blocks; R4 proved 256 is worse).
//      EARLY stress: QUAD threads (R6/R7: halves VALU), rows 3..33 x quads 1..7
//      (cols 4..31 -- the R7-proven causal region), 8-lane row stride (lane7 idle)
//      so wave rows are aligned. SSW=52 (odd multiple of 4): stride-48's
//      rows-alias-every-2 bank conflict on the vel phase's stress reads is gone.
//      LATE stress: per-CELL scalar over the 501 remaining cells with INLINE
//      dense cohstore publish (the only publish pattern that measured clean:
//      R6 quad-sparse = 3x write amp; R9 asm sc1 = stale reads + 3x amp).
static constexpr int TB = 8, TS = 37;
static constexpr int NBLK = TB * TB * NS;      // 128
static constexpr int NTHR = 512;
static constexpr int SVW = 44, VROWS = 41;     // vel region 41x41, stride 44 (odd x4)
static constexpr int SSW = 52, SROWS = 45;     // stress region 45x45, stride 52 (odd x4)
// vel quads: 41 rows x 11 quads = 451.  interior (rows 4..37, quads 1..8) = 272.
static constexpr int NVINT = 272, NVTOT = 451;
static constexpr int SFRAME = 656;             // 45^2 - 37^2 frame cells
// stress EARLY: tid 0..247 -> rows 3..33 (tid>>3), lanes 0..6 = quads 1..7, lane7 idle
static constexpr int NSE = 248;
// stress LATE (per-cell): 222 full-ring-row cells + 279 strip cells = 501
static constexpr int NLATE = 501;
// publish-only slots: early's ring rows 3,33 x cells 4..31 (2 x 28)
static constexpr int NPUBX = 56;

// ---- global ws layout (floats): parity-double-buffered stress + flags + vmax slots ----
// NO memset needed: flags poison (0xAAAAAAAA) reads as negative int = "not ready";
// vmax slots poison has sign bit set = "not written" (real values are positive floats).
static constexpr int GSLOT   = 3 * NS * NCELL;
static constexpr int FLG_OFF = 2 * GSLOT;

__device__ __forceinline__ float cohload(const float* p) {
    return __hip_atomic_load(p, __ATOMIC_RELAXED, __HIP_MEMORY_SCOPE_AGENT);
}
__device__ __forceinline__ void cohstore(float* p, float v) {
    __hip_atomic_store(p, v, __ATOMIC_RELAXED, __HIP_MEMORY_SCOPE_AGENT);
}

// 8-float window load as 2 aligned float4s into a statically-indexed register array
// (function, not macro: a macro parameter named w would capture the .w member token)
__device__ __forceinline__ void ld8(float* __restrict__ dst,
                                    const float* __restrict__ arr, int idx) {
    float4 A_ = *(const float4*)&arr[idx];
    float4 B_ = *(const float4*)&arr[idx + 4];
    dst[0] = A_.x; dst[1] = A_.y; dst[2] = A_.z; dst[3] = A_.w;
    dst[4] = B_.x; dst[5] = B_.y; dst[6] = B_.z; dst[7] = B_.w;
}

__global__ __launch_bounds__(NTHR, 1)
void elastic_fused(const float* __restrict__ lamb, const float* __restrict__ mu,
                   const float* __restrict__ buoy, const float* __restrict__ amps,
                   const int* __restrict__ src_loc, const int* __restrict__ rec_loc,
                   float* __restrict__ out, float* __restrict__ ws)
{
    __shared__ __align__(16) float sSyy[SROWS * SSW];
    __shared__ __align__(16) float sSxy[SROWS * SSW];
    __shared__ __align__(16) float sSxx[SROWS * SSW];
    __shared__ __align__(16) float sVy[VROWS * SVW];
    __shared__ __align__(16) float sVx[VROWS * SVW];
    __shared__ float sAmp[NSRC * NT];    // (first reused as uint sred[NBLK] for vmax)
    __shared__ float wmax[NTHR / 64];
    __shared__ int   rcnt;
    __shared__ short rl_r[NREC];
    __shared__ int   rl_pos[NREC];

    int* flags = (int*)(ws + FLG_OFF);
    unsigned* gvm = (unsigned*)(flags + NBLK);
    float* gstr = ws;

    const int tid  = threadIdx.x;
    const int shot = blockIdx.x & 1;
    const int tb   = blockIdx.x >> 1;
    const int bty  = tb >> 3, btx = tb & 7;
    const int gy0  = bty * TS, gx0 = btx * TS;
    const int myBlk = blockIdx.x;

    // poll thread -> one spatial neighbor (same shot); frame touches corners -> all 8
    int myNbr = -1;
    if (tid < 8) {
        int idx = tid < 4 ? tid : tid + 1;
        int dy = idx / 3 - 1, dx = idx % 3 - 1;
        int nty = bty + dy, ntx = btx + dx;
        if (nty >= 0 && nty < TB && ntx >= 0 && ntx < TB)
            myNbr = ((nty * TB + ntx) << 1) | shot;
    }

    // ---- zero LDS fields (incl. pad cols; global stress bufs need no init: t0 frame=0) ----
    for (int i = tid; i < SROWS * SSW; i += NTHR) { sSyy[i] = 0.0f; sSxy[i] = 0.0f; sSxx[i] = 0.0f; }
    for (int i = tid; i < VROWS * SVW; i += NTHR) { sVy[i] = 0.0f; sVx[i] = 0.0f; }
    if (tid == 0) rcnt = 0;

    // ---- distributed vmax (bit-identical: uint-max == float-max for positives) ----
    {
        int i = myBlk * NTHR + tid;     // 128 * 512 = 65536 = NYI*NYI exactly
        float v = (lamb[i] + 2.0f * mu[i]) * buoy[i];
        #pragma unroll
        for (int off = 32; off > 0; off >>= 1)
            v = fmaxf(v, __shfl_down(v, off));
        if ((tid & 63) == 0) wmax[tid >> 6] = v;
    }

    // ---- vel quad mapping (phase-packed: interior quads first; 8 quads/row) ----
    const bool vact = tid < NVTOT;
    const bool vint = tid < NVINT;
    int vrow = 0, vq = 0;
    if (vint) { vrow = 4 + tid / 8; vq = 1 + (tid & 7); }
    else if (vact) {
        int j = tid - NVINT;
        if (j < 44)      { vrow = j / 11; vq = j % 11; }
        else if (j < 77) { int k = j - 44; vrow = 38 + k / 11; vq = k % 11; }
        else             { int k = j - 77; vrow = 4 + k / 3; int c = k % 3;
                           vq = (c == 0) ? 0 : (c == 1 ? 9 : 10); }
    }
    const int c0v = 4 * vq;
    const int gyv = gy0 - 2 + vrow;

    // hoist source coords
    int sly[NSRC], slx[NSRC];
    #pragma unroll
    for (int s = 0; s < NSRC; ++s) {
        sly[s] = src_loc[(shot * NSRC + s) * 2 + 0] + PMLW;
        slx[s] = src_loc[(shot * NSRC + s) * 2 + 1] + PMLW;
    }

    int vdm = 0, smk4 = 0;
    float buo[4];
    #pragma unroll
    for (int m = 0; m < 4; ++m) {
        int vx_ = c0v + m;
        int gx = gx0 - 2 + vx_;
        bool ing = vact && vx_ <= 40 && gyv >= 0 && gyv < NY && gx >= 0 && gx < NX;
        if (ing) vdm |= 1 << m;
        float b = 0.0f;
        if (ing) {
            int iy = min(max(gyv - PMLW, 0), NYI - 1);
            int ix = min(max(gx - PMLW, 0), NYI - 1);
            b = buoy[iy * NYI + ix];
        }
        buo[m] = b;
        #pragma unroll
        for (int s = 0; s < NSRC; ++s)
            if (ing && sly[s] == gyv && slx[s] == gx) smk4 |= 1 << (m * 8 + s);
    }

    // ---- EARLY stress: rows 3..33, quads 1..7, 8-lane row stride (lane7 idle).
    //      Causality (R7-proven): cells rows 3..33 x cols 4..31 only. No publish. ----
    const bool sE = (tid < NSE) && ((tid & 7) != 7);
    const int trowE = sE ? 3 + (tid >> 3) : 3;
    const int tqE   = sE ? 1 + (tid & 7) : 1;
    const int q0E   = 4 * tqE;
    float lamE[4], muvE[4], l2mE[4];
    #pragma unroll
    for (int m = 0; m < 4; ++m) {
        float la = 0.0f, mm_ = 0.0f;
        if (sE) {
            int iy = min(max(gy0 + trowE - PMLW, 0), NYI - 1);
            int ix = min(max(gx0 + q0E + m - PMLW, 0), NYI - 1);
            la = lamb[iy * NYI + ix];
            mm_ = mu[iy * NYI + ix];
        }
        lamE[m] = la; muvE[m] = mm_; l2mE[m] = la + 2.0f * mm_;
    }

    // ---- LATE stress: per-cell scalar over the 501 remaining cells:
    //      [0,222): full ring rows {0,1,2,34,35,36} x cols 0..36
    //      [222,501): strip rows 3..33 x cols {0..3, 32..36} ----
    const bool sL = tid < NLATE;
    int trowL = 0, txL = 0;
    if (sL) {
        if (tid < 222) { int r6 = tid / 37; trowL = r6 < 3 ? r6 : 31 + r6; txL = tid % 37; }
        else           { int k = tid - 222; trowL = 3 + k / 9; int c = k % 9;
                         txL = c < 4 ? c : 28 + c; }
    }
    const bool pubL = sL && (trowL < 4 || trowL >= 33 || txL < 4 || txL >= 33);
    const int sidxL = (trowL + 4) * SSW + (txL + 4);
    const int vidxL = (trowL + 2) * SVW + (txL + 2);
    const int gidxL = (gy0 + trowL) * NX + gx0 + txL;
    float lamLs = 0.0f, muLs = 0.0f, l2mLs = 0.0f;
    if (sL) {
        int iy = min(max(gy0 + trowL - PMLW, 0), NYI - 1);
        int ix = min(max(gx0 + txL - PMLW, 0), NYI - 1);
        lamLs = lamb[iy * NYI + ix];
        muLs  = mu[iy * NYI + ix];
        l2mLs = lamLs + 2.0f * muLs;
    }

    // ---- publish-only slots: early's ring rows 3,33 x cells 4..31 (read from LDS) ----
    const bool pX = tid < NPUBX;
    const int trX = (tid < 28) ? 3 : 33;
    const int txX = 4 + (tid < 28 ? tid : tid - 28);
    const int lX  = (trX + 4) * SSW + (txX + 4);
    const int gX  = (gy0 + trX) * NX + gx0 + txX;

    // ---- frame-slot geometry (2 slots; stride SSW) ----
    bool fval[2], fin[2];
    int  flidx[2], fgi[2];
    #pragma unroll
    for (int k = 0; k < 2; ++k) {
        int ff = tid + NTHR * k;
        fval[k] = ff < SFRAME;
        int fy = 0, fx = 0;
        if (fval[k]) {
            if (ff < 4 * SROWS)      { fy = ff / SROWS; fx = ff - fy * SROWS; }
            else if (ff < 8 * SROWS) { int r = ff - 4 * SROWS; fy = 41 + r / SROWS; fx = r % SROWS; }
            else {
                int r = ff - 8 * SROWS;
                if (r < 37 * 4) { fy = 4 + (r >> 2); fx = r & 3; }
                else { r -= 37 * 4; fy = 4 + (r >> 2); fx = 41 + (r & 3); }
            }
        }
        int gy = gy0 - 4 + fy, gx = gx0 - 4 + fx;
        fin[k]   = fval[k] && gy >= 0 && gy < NY && gx >= 0 && gx < NX;
        flidx[k] = fy * SSW + fx;
        fgi[k]   = fin[k] ? (gy * NX + gx) : 0;
    }

    __syncthreads();   // wmax partials + LDS zeros + rcnt=0 visible

    // ---- grid all-reduce of vmax via poison-safe per-block slots ----
    if (tid == 0) {
        float v = wmax[0];
        #pragma unroll
        for (int w = 1; w < NTHR / 64; ++w) v = fmaxf(v, wmax[w]);
        __hip_atomic_store(&gvm[myBlk], __float_as_uint(v), __ATOMIC_RELAXED,
                           __HIP_MEMORY_SCOPE_AGENT);
    }
    unsigned* sred = (unsigned*)sAmp;
    if (tid < NBLK) {
        unsigned v;
        for (;;) {
            v = __hip_atomic_load(&gvm[tid], __ATOMIC_RELAXED, __HIP_MEMORY_SCOPE_AGENT);
            if (!(v & 0x80000000u)) break;
            __builtin_amdgcn_s_sleep(1);
        }
        sred[tid] = v;
    }
    __syncthreads();
    if (tid == 0) {
        unsigned mb = sred[0];
        for (int i = 1; i < NBLK; ++i) mb = mb > sred[i] ? mb : sred[i];
        wmax[0] = __uint_as_float(mb);
    }
    __syncthreads();

    // ---- per-thread CPML profile tables (registers; no LDS table reads in loop) ----
    const float max_vel = sqrtf(wmax[0]);
    const float sig_max = 3.0f * max_vel * logf(1000.0f) / (2.0f * PMLW * DXF);
    auto prof = [&](int g) -> float {
        float fi = (float)g;
        float d1 = fmaxf((float)PMLW - fi, 0.0f);
        float d2 = fmaxf(fi - (float)(NY - 1 - PMLW), 0.0f);
        float dd = fmaxf(d1, d2) * (1.0f / (float)PMLW);
        return expf(-(sig_max * dd * dd) * DTF);
    };
    const float byv = prof(gyv), ayv = byv - 1.0f;
    const float bysE = prof(gy0 + trowE), aysE = bysE - 1.0f;
    const float bysL = prof(gy0 + trowL), aysL = bysL - 1.0f;
    const float bxsL = prof(gx0 + txL),   axsL = bxsL - 1.0f;
    float bxv[4], axv[4], bxsE[4], axsE[4];
    #pragma unroll
    for (int m = 0; m < 4; ++m) {
        bxv[m]  = prof(gx0 - 2 + c0v + m); axv[m]  = bxv[m]  - 1.0f;
        bxsE[m] = prof(gx0 + q0E + m);     axsE[m] = bxsE[m] - 1.0f;
    }

    if (tid < NREC) {
        int r = tid;
        int ry = rec_loc[(shot * NREC + r) * 2 + 0] + PMLW;
        int rx = rec_loc[(shot * NREC + r) * 2 + 1] + PMLW;
        if (ry >= gy0 && ry < gy0 + TS && rx >= gx0 && rx < gx0 + TS) {
            int p = atomicAdd(&rcnt, 1);
            rl_r[p]   = (short)r;
            rl_pos[p] = (ry - gy0 + 2) * SVW + (rx - gx0 + 2);
        }
    }
    __syncthreads();   // sred reads done before sAmp overwrite
    for (int i = tid; i < NSRC * NT; i += NTHR)
        sAmp[i] = amps[shot * NSRC * NT + i];
    __syncthreads();

    // ---- CPML memory state (registers, statically indexed) ----
    float msyyy[4] = {0,0,0,0}, msxyx[4] = {0,0,0,0};
    float msxyy[4] = {0,0,0,0}, msxxx[4] = {0,0,0,0};
    float mvyyE[4] = {0,0,0,0}, mvxxE[4] = {0,0,0,0}, mvyxE[4] = {0,0,0,0}, mvxyE[4] = {0,0,0,0};
    float mvyyLs = 0.0f, mvxxLs = 0.0f, mvyxLs = 0.0f, mvxyLs = 0.0f;

    // velocity quad: 8-float windows, expression-identical per-cell math
    auto vel_quad = [&](int t) {
        const int sb = vrow * SSW + c0v;     // window row 0 = S-row vy_ (taps rows vy_..vy_+3)
        float r0[8], r1[8], r2[8], r3[8];
        float dsyy_y[4], dsxy_x[4], dsxy_y[4], dsxx_x[4];
        ld8(r0, sSyy, sb); ld8(r1, sSyy, sb + SSW);
        ld8(r2, sSyy, sb + 2 * SSW); ld8(r3, sSyy, sb + 3 * SSW);
        #pragma unroll
        for (int m = 0; m < 4; ++m)
            dsyy_y[m] = (FC1 * (r2[m+2] - r1[m+2]) + FC2 * (r3[m+2] - r0[m+2])) * INV_DX;
        ld8(r0, sSxy, sb); ld8(r1, sSxy, sb + SSW);
        ld8(r2, sSxy, sb + 2 * SSW); ld8(r3, sSxy, sb + 3 * SSW);
        #pragma unroll
        for (int m = 0; m < 4; ++m) {
            dsxy_y[m] = (FC1 * (r2[m+2] - r1[m+2]) + FC2 * (r3[m+2] - r0[m+2])) * INV_DX;
            dsxy_x[m] = (FC1 * (r2[m+2] - r2[m+1]) + FC2 * (r2[m+3] - r2[m])) * INV_DX;
        }
        ld8(r0, sSxx, sb + 2 * SSW);         // x-deriv needs only the center row
        #pragma unroll
        for (int m = 0; m < 4; ++m)
            dsxx_x[m] = (FC1 * (r0[m+2] - r0[m+1]) + FC2 * (r0[m+3] - r0[m])) * INV_DX;

        const int vb = vrow * SVW + c0v;
        float4 oy4 = *(const float4*)&sVy[vb];
        float4 ox4 = *(const float4*)&sVx[vb];
        float ovy[4] = {oy4.x, oy4.y, oy4.z, oy4.w};
        float ovx[4] = {ox4.x, ox4.y, ox4.z, ox4.w};
        float nvy[4], nvx[4];
        #pragma unroll
        for (int m = 0; m < 4; ++m) {
            float mm;
            mm = byv * msyyy[m] + ayv * dsyy_y[m];      msyyy[m] = mm; float dy1 = dsyy_y[m] + mm;
            mm = bxv[m] * msxyx[m] + axv[m] * dsxy_x[m]; msxyx[m] = mm; float dx1 = dsxy_x[m] + mm;
            mm = byv * msxyy[m] + ayv * dsxy_y[m];      msxyy[m] = mm; float dy2 = dsxy_y[m] + mm;
            mm = bxv[m] * msxxx[m] + axv[m] * dsxx_x[m]; msxxx[m] = mm; float dx2 = dsxx_x[m] + mm;
            nvy[m] = ovy[m] + DTF * buo[m] * (dy1 + dx1);
            nvx[m] = ovx[m] + DTF * buo[m] * (dy2 + dx2);
        }
        if (smk4) {
            #pragma unroll
            for (int m = 0; m < 4; ++m) {
                #pragma unroll
                for (int s = 0; s < NSRC; ++s)
                    if ((smk4 >> (m * 8 + s)) & 1) nvy[m] += DTF * buo[m] * sAmp[s * NT + t];
            }
        }
        if (vdm == 0xF) {
            *(float4*)&sVy[vb] = make_float4(nvy[0], nvy[1], nvy[2], nvy[3]);
            *(float4*)&sVx[vb] = make_float4(nvx[0], nvx[1], nvx[2], nvx[3]);
        } else {
            #pragma unroll
            for (int m = 0; m < 4; ++m)
                if ((vdm >> m) & 1) { sVy[vb + m] = nvy[m]; sVx[vb + m] = nvx[m]; }
        }
    };

    // EARLY stress body: rows 3..33 x quads 1..7, LDS only
    auto stress_early = [&]() {
        const int vb = (trowE + 1) * SVW + q0E;
        float y0[8], y1[8], y2[8], y3[8];
        float dvy_y[4], dvy_x[4], dvx_y[4], dvx_x[4];
        ld8(y0, sVy, vb); ld8(y1, sVy, vb + SVW);
        ld8(y2, sVy, vb + 2 * SVW); ld8(y3, sVy, vb + 3 * SVW);
        #pragma unroll
        for (int m = 0; m < 4; ++m) {
            dvy_y[m] = (FC1 * (y2[m+2] - y1[m+2]) + FC2 * (y3[m+2] - y0[m+2])) * INV_DX;
            dvy_x[m] = (FC1 * (y1[m+3] - y1[m+2]) + FC2 * (y1[m+4] - y1[m+1])) * INV_DX;
        }
        ld8(y0, sVx, vb); ld8(y1, sVx, vb + SVW);
        ld8(y2, sVx, vb + 2 * SVW); ld8(y3, sVx, vb + 3 * SVW);
        #pragma unroll
        for (int m = 0; m < 4; ++m) {
            dvx_x[m] = (FC1 * (y1[m+3] - y1[m+2]) + FC2 * (y1[m+4] - y1[m+1])) * INV_DX;
            dvx_y[m] = (FC1 * (y2[m+2] - y1[m+2]) + FC2 * (y3[m+2] - y0[m+2])) * INV_DX;
        }
        const int sb = (trowE + 4) * SSW + q0E + 4;
        float4 a4 = *(const float4*)&sSyy[sb];
        float4 b4 = *(const float4*)&sSxy[sb];
        float4 c4 = *(const float4*)&sSxx[sb];
        float os0[4] = {a4.x, a4.y, a4.z, a4.w};
        float os1[4] = {b4.x, b4.y, b4.z, b4.w};
        float os2[4] = {c4.x, c4.y, c4.z, c4.w};
        float nsyy[4], nsxy[4], nsxx[4];
        #pragma unroll
        for (int m = 0; m < 4; ++m) {
            float mm;
            mm = bysE * mvyyE[m] + aysE * dvy_y[m];        mvyyE[m] = mm; float fy = dvy_y[m] + mm;
            mm = bxsE[m] * mvxxE[m] + axsE[m] * dvx_x[m];  mvxxE[m] = mm; float fx = dvx_x[m] + mm;
            nsyy[m] = os0[m] + DTF * (l2mE[m] * fy + lamE[m] * fx);
            nsxx[m] = os2[m] + DTF * (lamE[m] * fy + l2mE[m] * fx);
            mm = bxsE[m] * mvyxE[m] + axsE[m] * dvy_x[m];  mvyxE[m] = mm; float gx_ = dvy_x[m] + mm;
            mm = bysE * mvxyE[m] + aysE * dvx_y[m];        mvxyE[m] = mm; float gy_ = dvx_y[m] + mm;
            nsxy[m] = os1[m] + DTF * muvE[m] * (gx_ + gy_);
        }
        *(float4*)&sSyy[sb] = make_float4(nsyy[0], nsyy[1], nsyy[2], nsyy[3]);
        *(float4*)&sSxy[sb] = make_float4(nsxy[0], nsxy[1], nsxy[2], nsxy[3]);
        *(float4*)&sSxx[sb] = make_float4(nsxx[0], nsxx[1], nsxx[2], nsxx[3]);
    };

    // LATE stress body: per-cell scalar (baseline-proven math), inline dense publish
    auto stress_late = [&](float* gsw) {
        float d, mm;
        d = (FC1 * (sVy[vidxL + SVW] - sVy[vidxL]) + FC2 * (sVy[vidxL + 2 * SVW] - sVy[vidxL - SVW])) * INV_DX;
        mm = bysL * mvyyLs + aysL * d;  mvyyLs = mm;  float dvy_y = d + mm;
        d = (FC1 * (sVx[vidxL + 1] - sVx[vidxL]) + FC2 * (sVx[vidxL + 2] - sVx[vidxL - 1])) * INV_DX;
        mm = bxsL * mvxxLs + axsL * d;  mvxxLs = mm;  float dvx_x = d + mm;
        float nsyy = sSyy[sidxL] + DTF * (l2mLs * dvy_y + lamLs * dvx_x);
        float nsxx = sSxx[sidxL] + DTF * (lamLs * dvy_y + l2mLs * dvx_x);
        d = (FC1 * (sVy[vidxL + 1] - sVy[vidxL]) + FC2 * (sVy[vidxL + 2] - sVy[vidxL - 1])) * INV_DX;
        mm = bxsL * mvyxLs + axsL * d;  mvyxLs = mm;  float dvy_x = d + mm;
        d = (FC1 * (sVx[vidxL + SVW] - sVx[vidxL]) + FC2 * (sVx[vidxL + 2 * SVW] - sVx[vidxL - SVW])) * INV_DX;
        mm = bysL * mvxyLs + aysL * d;  mvxyLs = mm;  float dvx_y = d + mm;
        float nsxy = sSxy[sidxL] + DTF * muLs * (dvy_x + dvx_y);
        sSyy[sidxL] = nsyy; sSxy[sidxL] = nsxy; sSxx[sidxL] = nsxx;
        if (pubL) {
            cohstore(&gsw[(0 * NS + shot) * NCELL + gidxL], nsyy);
            cohstore(&gsw[(1 * NS + shot) * NCELL + gidxL], nsxy);
            cohstore(&gsw[(2 * NS + shot) * NCELL + gidxL], nsxx);
        }
    };

    // ========== time loop (4 barriers, baseline structure):
    // [vel-int | poll] B1 [frame loads; EARLY stress overlaps latency; frame->LDS]
    // B2 [vel-bnd] B3 [recv; LATE stress + inline publish; publish-extra] B4 [flag].
    // Disjointness (R7-proven): EARLY writes rows 3..33 x cols 4..31; boundary-vel
    // stress taps lie outside that set in the offending coordinate. ==========
    for (int t = 0; t < NT; ++t) {
        const float* gsr = gstr + ((t + 1) & 1) * GSLOT;
        float*       gsw = gstr + (t & 1) * GSLOT;

        // interior velocity (waves 0..4): no frame dependency
        if (vint) vel_quad(t);

        if (t > 0 && myNbr >= 0) {
            while (__hip_atomic_load(&flags[myNbr], __ATOMIC_RELAXED,
                                     __HIP_MEMORY_SCOPE_AGENT) < t)
                __builtin_amdgcn_s_sleep(1);
        }
        __syncthreads();   // B1

        // issue frame loads; early stress overlaps their latency
        float fr0[3], fr1[3];
        #pragma unroll
        for (int f = 0; f < 3; ++f) {
            fr0[f] = (t > 0 && fin[0]) ? cohload(&gsr[(f * NS + shot) * NCELL + fgi[0]]) : 0.0f;
            fr1[f] = (t > 0 && fin[1]) ? cohload(&gsr[(f * NS + shot) * NCELL + fgi[1]]) : 0.0f;
        }

        if (sE) stress_early();

        if (fval[0]) { sSyy[flidx[0]] = fr0[0]; sSxy[flidx[0]] = fr0[1]; sSxx[flidx[0]] = fr0[2]; }
        if (fval[1]) { sSyy[flidx[1]] = fr1[0]; sSxy[flidx[1]] = fr1[1]; sSxx[flidx[1]] = fr1[2]; }
        __syncthreads();   // B2

        // boundary velocity (needs frame)
        if (vact && !vint) vel_quad(t);
        __syncthreads();   // B3

        if (tid < rcnt)
            out[(shot * NREC + rl_r[tid]) * NT + t] = sVy[rl_pos[tid]];

        if (sL) stress_late(gsw);
        // publish early's ring rows 3,33 (values in LDS since B2; cells not touched by LATE)
        if (pX) {
            cohstore(&gsw[(0 * NS + shot) * NCELL + gX], sSyy[lX]);
            cohstore(&gsw[(1 * NS + shot) * NCELL + gX], sSxy[lX]);
            cohstore(&gsw[(2 * NS + shot) * NCELL + gX], sSxx[lX]);
        }

        // publish: syncthreads drains all waves' ring stores (vmcnt(0)) -> flag store
        __syncthreads();   // B4
        if (tid == 0 && t < NT - 1)
            __hip_atomic_store(&flags[myBlk], t + 1, __ATOMIC_RELAXED,
                               __HIP_MEMORY_SCOPE_AGENT);
    }
}

extern "C" void kernel_launch(void* const* d_in, const int* in_sizes, int n_in,
                              void* d_out, int out_size, void* d_ws, size_t ws_size,
                              hipStream_t stream) {
    const float* lamb    = (const float*)d_in[0];
    const float* mu      = (const float*)d_in[1];
    const float* buoy    = (const float*)d_in[2];
    const float* amps    = (const float*)d_in[3];
    const int*   src_loc = (const int*)d_in[4];
    const int*   rec_loc = (const int*)d_in[5];
    float* ws  = (float*)d_ws;
    float* out = (float*)d_out;

    // No memset needed: flags/vmax-slots are poison-tolerant (see ws layout comment).
    elastic_fused<<<NBLK, NTHR, 0, stream>>>(lamb, mu, buoy, amps, src_loc, rec_loc, out, ws);
}

// Round 11
// 329.494 us; speedup vs baseline: 1.3817x; 1.0845x over previous
//
#include <hip/hip_runtime.h>
#include <math.h>

// ---- problem constants (match reference) ----
static constexpr int NYI  = 256;
static constexpr int PMLW = 20;
static constexpr int NY   = 296, NX = 296;
static constexpr int NCELL = NY * NX;
static constexpr int NS   = 2;
static constexpr int NSRC = 8;
static constexpr int NREC = 64;
static constexpr int NT   = 64;
static constexpr float DXF = 4.0f;
static constexpr float DTF = 5e-4f;
static constexpr float FC1 = 9.0f / 8.0f;
static constexpr float FC2 = -1.0f / 24.0f;
static constexpr float INV_DX = 1.0f / DXF;

// ---- decomposition: 8x8 tiles of 37x37, one shot per block ----
// SESSION CONSOLIDATION (R10 post-mortem): dur ~= 235us structural latency floor
// (64 steps x {4 barrier drains + coherent ring-store drain + flag visibility +
// poll + frame-load latency}) + compute-serial. This variant (R3) is the best
// measured: per-cell phases (lowest conflicts 0.92e7), distributed vmax,
// frame-load latency hidden under interior stress. Quad-compute variants
// (R6-R10) halved VALU but never beat this on wall-clock; sync-structure
// changes (R1/R4/R8/R9) regressed or broke numerics.
static constexpr int TB = 8, TS = 37;          // 8*37 = 296 exactly
static constexpr int VS = TS + 4;              // 41: vel region (tile+2 halo, redundant)
static constexpr int SS = TS + 8;              // 45: stress region (tile+4 halo)
static constexpr int NBLK = TB * TB * NS;      // 128
static constexpr int NTHR = 512;
static constexpr int VAREA = VS * VS;          // 1681
static constexpr int TAREA = TS * TS;          // 1369
static constexpr int SFRAME = SS * SS - TAREA; // 656 frame cells
static constexpr int KV = 4, KT = 3;

// ---- global ws layout (floats): parity-double-buffered stress + flags + vmax slots ----
// NO memset needed: flags poison (0xAAAAAAAA) reads as negative int = "not ready";
// vmax slots poison has sign bit set = "not written" (real values are positive floats).
static constexpr int GSLOT   = 3 * NS * NCELL;       // one parity buffer
static constexpr int FLG_OFF = 2 * GSLOT;            // int flags[NBLK]; uint gvm[NBLK]

__device__ __forceinline__ float cohload(const float* p) {
    return __hip_atomic_load(p, __ATOMIC_RELAXED, __HIP_MEMORY_SCOPE_AGENT);
}
__device__ __forceinline__ void cohstore(float* p, float v) {
    __hip_atomic_store(p, v, __ATOMIC_RELAXED, __HIP_MEMORY_SCOPE_AGENT);
}

__global__ __launch_bounds__(NTHR, 1)
void elastic_fused(const float* __restrict__ lamb, const float* __restrict__ mu,
                   const float* __restrict__ buoy, const float* __restrict__ amps,
                   const int* __restrict__ src_loc, const int* __restrict__ rec_loc,
                   float* __restrict__ out, float* __restrict__ ws)
{
    __shared__ float sS[3][SS * SS];     // syy,sxy,sxx  (center computed, frame from neighbors)
    __shared__ float sV[2][VS * VS];     // vy,vx        (all computed locally, halo redundant)
    __shared__ float byt[VS], ayt[VS], bxt[VS], axt[VS];
    __shared__ float sAmp[NSRC * NT];    // (first reused as uint sred[NBLK] for vmax)
    __shared__ float wmax[NTHR / 64];
    __shared__ int   rcnt;
    __shared__ short rl_r[NREC];
    __shared__ int   rl_pos[NREC];

    int* flags = (int*)(ws + FLG_OFF);
    unsigned* gvm = (unsigned*)(flags + NBLK);
    float* gstr = ws;

    const int tid  = threadIdx.x;
    const int shot = blockIdx.x & 1;
    const int tb   = blockIdx.x >> 1;
    const int bty  = tb >> 3, btx = tb & 7;
    const int gy0  = bty * TS, gx0 = btx * TS;
    const int myBlk = blockIdx.x;

    // poll thread -> one spatial neighbor (same shot); frame touches corners, so all 8
    int myNbr = -1;
    if (tid < 8) {
        int idx = tid < 4 ? tid : tid + 1;          // skip center of 3x3
        int dy = idx / 3 - 1, dx = idx % 3 - 1;
        int nty = bty + dy, ntx = btx + dx;
        if (nty >= 0 && nty < TB && ntx >= 0 && ntx < TB)
            myNbr = ((nty * TB + ntx) << 1) | shot;
    }

    // ---- zero LDS fields (global stress buffers need NO init: t==0 frame forced 0) ----
    for (int i = tid; i < 3 * SS * SS; i += NTHR) ((float*)sS)[i] = 0.0f;
    for (int i = tid; i < 2 * VS * VS; i += NTHR) ((float*)sV)[i] = 0.0f;
    if (tid == 0) rcnt = 0;

    // ---- DISTRIBUTED max wave speed: each block scans 512 of the 65536 interior
    //      cells (1 per thread); grid all-reduce via per-block slots (poison-safe:
    //      positive-float bits have sign bit 0, poison 0xAAAAAAAA has sign bit 1).
    //      uint-max == float-max for positive floats -> bit-identical result. ----
    {
        int i = myBlk * NTHR + tid;     // 128 blocks * 512 = 65536 = NYI*NYI exactly
        float v = (lamb[i] + 2.0f * mu[i]) * buoy[i];
        #pragma unroll
        for (int off = 32; off > 0; off >>= 1)
            v = fmaxf(v, __shfl_down(v, off));
        if ((tid & 63) == 0) wmax[tid >> 6] = v;
    }

    // ---- per-thread V-region slots (vel + its CPML memories, redundant halo-2) ----
    int   sidx_v[KV], vyv[KV], vxv[KV], smk[KV];
    float buo_v[KV];
    float msyyy[KV] = {0,0,0,0}, msxyx[KV] = {0,0,0,0};
    float msxyy[KV] = {0,0,0,0}, msxxx[KV] = {0,0,0,0};
    unsigned cvm = 0, intm = 0;
    #pragma unroll
    for (int k = 0; k < KV; ++k) {
        int vi = tid + NTHR * k;
        bool val = vi < VAREA;
        int vy_ = val ? vi / VS : 0;
        int vx_ = val ? vi - vy_ * VS : 0;
        int gy = gy0 - 2 + vy_, gx = gx0 - 2 + vx_;
        bool ing = val && gy >= 0 && gy < NY && gx >= 0 && gx < NX;
        if (ing) cvm |= 1u << k;
        // interior: stencil S-rows [vy,vy+3], S-cols [vx,vx+3] all inside [4,41)
        if (ing && vy_ >= 4 && vy_ <= 37 && vx_ >= 4 && vx_ <= 37) intm |= 1u << k;
        vyv[k] = vy_; vxv[k] = vx_;
        sidx_v[k] = (vy_ + 2) * SS + (vx_ + 2);
        float b = 0.0f;
        if (ing) {
            int iy = min(max(gy - PMLW, 0), NYI - 1);
            int ix = min(max(gx - PMLW, 0), NYI - 1);
            b = buoy[iy * NYI + ix];
        }
        buo_v[k] = b;
        int sm = 0;
        #pragma unroll
        for (int s = 0; s < NSRC; ++s) {
            int sy = src_loc[(shot * NSRC + s) * 2 + 0] + PMLW;
            int sx = src_loc[(shot * NSRC + s) * 2 + 1] + PMLW;
            if (ing && sy == gy && sx == gx) sm |= 1 << s;
        }
        smk[k] = sm;
    }
    const unsigned bndm = cvm & ~intm;

    // ---- per-thread tile slots (stress + its CPML memories, owned) ----
    int   sidx_t[KT], vidx_t[KT], gidx_t[KT], tyt[KT], txt[KT];
    float lam_t[KT], mu_t[KT], l2m_t[KT];
    float mvyy[KT] = {0,0,0}, mvxx[KT] = {0,0,0}, mvyx[KT] = {0,0,0}, mvxy[KT] = {0,0,0};
    unsigned ctm = 0, ringm = 0;
    #pragma unroll
    for (int k = 0; k < KT; ++k) {
        int ti = tid + NTHR * k;
        bool val = ti < TAREA;
        int ty = val ? ti / TS : 0;
        int tx = val ? ti - ty * TS : 0;
        int gy = gy0 + ty, gx = gx0 + tx;
        if (val) ctm |= 1u << k;
        if (val && (ty < 4 || ty >= TS - 4 || tx < 4 || tx >= TS - 4)) ringm |= 1u << k;
        tyt[k] = ty; txt[k] = tx;
        sidx_t[k] = (ty + 4) * SS + (tx + 4);
        vidx_t[k] = (ty + 2) * VS + (tx + 2);
        gidx_t[k] = gy * NX + gx;
        float la = 0.0f, m = 0.0f;
        if (val) {
            int iy = min(max(gy - PMLW, 0), NYI - 1);
            int ix = min(max(gx - PMLW, 0), NYI - 1);
            la = lamb[iy * NYI + ix];
            m  = mu  [iy * NYI + ix];
        }
        lam_t[k] = la; mu_t[k] = m; l2m_t[k] = la + 2.0f * m;
    }

    // ---- per-thread frame-slot geometry (precomputed; P1 becomes pure loads) ----
    bool fval[2], fin[2];
    int  flidx[2], fgi[2];
    #pragma unroll
    for (int k = 0; k < 2; ++k) {
        int ff = tid + NTHR * k;
        fval[k] = ff < SFRAME;
        int fy = 0, fx = 0;
        if (fval[k]) {
            if (ff < 4 * SS)      { fy = ff / SS;                 fx = ff - fy * SS; }
            else if (ff < 8 * SS) { int r = ff - 4 * SS; fy = SS - 4 + r / SS; fx = r % SS; }
            else {
                int r = ff - 8 * SS;
                if (r < (SS - 8) * 4) { fy = 4 + (r >> 2); fx = r & 3; }
                else { r -= (SS - 8) * 4; fy = 4 + (r >> 2); fx = SS - 4 + (r & 3); }
            }
        }
        int gy = gy0 - 4 + fy, gx = gx0 - 4 + fx;
        fin[k]   = fval[k] && gy >= 0 && gy < NY && gx >= 0 && gx < NX;
        flidx[k] = fy * SS + fx;
        fgi[k]   = fin[k] ? (gy * NX + gx) : 0;
    }

    __syncthreads();   // wmax partials + LDS zeros + rcnt=0 visible in-block

    // ---- grid all-reduce of vmax via poison-safe per-block slots ----
    if (tid == 0) {
        float v = wmax[0];
        #pragma unroll
        for (int w = 1; w < NTHR / 64; ++w) v = fmaxf(v, wmax[w]);
        __hip_atomic_store(&gvm[myBlk], __float_as_uint(v), __ATOMIC_RELAXED,
                           __HIP_MEMORY_SCOPE_AGENT);
    }
    unsigned* sred = (unsigned*)sAmp;    // reuse sAmp space (loaded later)
    if (tid < NBLK) {
        unsigned v;
        for (;;) {
            v = __hip_atomic_load(&gvm[tid], __ATOMIC_RELAXED, __HIP_MEMORY_SCOPE_AGENT);
            if (!(v & 0x80000000u)) break;
            __builtin_amdgcn_s_sleep(1);
        }
        sred[tid] = v;
    }
    __syncthreads();   // all 128 partials in sred
    if (tid == 0) {
        unsigned mb = sred[0];
        for (int i = 1; i < NBLK; ++i) mb = mb > sred[i] ? mb : sred[i];
        wmax[0] = __uint_as_float(mb);   // uint-max == float-max (all positive)
    }
    __syncthreads();   // global vmax visible in wmax[0]

    const float max_vel = sqrtf(wmax[0]);
    const float sig_max = 3.0f * max_vel * logf(1000.0f) / (2.0f * PMLW * DXF);
    if (tid < VS) {
        auto prof = [&](int g) -> float {
            float fi = (float)g;
            float d1 = fmaxf((float)PMLW - fi, 0.0f);
            float d2 = fmaxf(fi - (float)(NY - 1 - PMLW), 0.0f);
            float dd = fmaxf(d1, d2) * (1.0f / (float)PMLW);
            return expf(-(sig_max * dd * dd) * DTF);
        };
        float b = prof(gy0 - 2 + tid); byt[tid] = b; ayt[tid] = b - 1.0f;
        b = prof(gx0 - 2 + tid);       bxt[tid] = b; axt[tid] = b - 1.0f;
    }
    if (tid < NREC) {
        int r = tid;
        int ry = rec_loc[(shot * NREC + r) * 2 + 0] + PMLW;
        int rx = rec_loc[(shot * NREC + r) * 2 + 1] + PMLW;
        if (ry >= gy0 && ry < gy0 + TS && rx >= gx0 && rx < gx0 + TS) {
            int p = atomicAdd(&rcnt, 1);
            rl_r[p]   = (short)r;
            rl_pos[p] = (ry - gy0 + 2) * VS + (rx - gx0 + 2);
        }
    }
    __syncthreads();   // sred reads done before sAmp overwrite
    for (int i = tid; i < NSRC * NT; i += NTHR)
        sAmp[i] = amps[shot * NSRC * NT + i];
    __syncthreads();   // tables + amps + receiver lists visible

    // velocity body over a slot mask (interior runs pre-wait, boundary post-frame-fill)
    auto do_vel = [&](unsigned m, int t) {
        #pragma unroll
        for (int k = 0; k < KV; ++k) {
            if (!((m >> k) & 1)) continue;
            int si = sidx_v[k];
            float by_ = byt[vyv[k]], ay_ = ayt[vyv[k]];
            float bx_ = bxt[vxv[k]], ax_ = axt[vxv[k]];
            float d, mm;
            d = (FC1 * (sS[0][si] - sS[0][si - SS]) + FC2 * (sS[0][si + SS] - sS[0][si - 2 * SS])) * INV_DX;
            mm = by_ * msyyy[k] + ay_ * d;  msyyy[k] = mm;  float dsyy_y = d + mm;
            d = (FC1 * (sS[1][si] - sS[1][si - 1]) + FC2 * (sS[1][si + 1] - sS[1][si - 2])) * INV_DX;
            mm = bx_ * msxyx[k] + ax_ * d;  msxyx[k] = mm;  float dsxy_x = d + mm;
            d = (FC1 * (sS[1][si] - sS[1][si - SS]) + FC2 * (sS[1][si + SS] - sS[1][si - 2 * SS])) * INV_DX;
            mm = by_ * msxyy[k] + ay_ * d;  msxyy[k] = mm;  float dsxy_y = d + mm;
            d = (FC1 * (sS[2][si] - sS[2][si - 1]) + FC2 * (sS[2][si + 1] - sS[2][si - 2])) * INV_DX;
            mm = bx_ * msxxx[k] + ax_ * d;  msxxx[k] = mm;  float dsxx_x = d + mm;
            int vi = tid + NTHR * k;
            float nvy = sV[0][vi] + DTF * buo_v[k] * (dsyy_y + dsxy_x);
            float nvx = sV[1][vi] + DTF * buo_v[k] * (dsxy_y + dsxx_x);
            if (smk[k]) {
                #pragma unroll
                for (int s = 0; s < NSRC; ++s)
                    if ((smk[k] >> s) & 1) nvy += DTF * buo_v[k] * sAmp[s * NT + t];
            }
            sV[0][vi] = nvy;
            sV[1][vi] = nvx;
        }
    };

    // stress body over a slot mask; pub=true publishes ring cells to global
    auto do_stress = [&](unsigned m, bool pub, float* gsw) {
        #pragma unroll
        for (int k = 0; k < KT; ++k) {
            if (!((m >> k) & 1)) continue;
            int si = sidx_t[k], vi = vidx_t[k];
            float by_ = byt[tyt[k] + 2], ay_ = ayt[tyt[k] + 2];
            float bx_ = bxt[txt[k] + 2], ax_ = axt[txt[k] + 2];
            float d, mm;
            d = (FC1 * (sV[0][vi + VS] - sV[0][vi]) + FC2 * (sV[0][vi + 2 * VS] - sV[0][vi - VS])) * INV_DX;
            mm = by_ * mvyy[k] + ay_ * d;  mvyy[k] = mm;  float dvy_y = d + mm;
            d = (FC1 * (sV[1][vi + 1] - sV[1][vi]) + FC2 * (sV[1][vi + 2] - sV[1][vi - 1])) * INV_DX;
            mm = bx_ * mvxx[k] + ax_ * d;  mvxx[k] = mm;  float dvx_x = d + mm;
            float nsyy = sS[0][si] + DTF * (l2m_t[k] * dvy_y + lam_t[k] * dvx_x);
            float nsxx = sS[2][si] + DTF * (lam_t[k] * dvy_y + l2m_t[k] * dvx_x);
            d = (FC1 * (sV[0][vi + 1] - sV[0][vi]) + FC2 * (sV[0][vi + 2] - sV[0][vi - 1])) * INV_DX;
            mm = bx_ * mvyx[k] + ax_ * d;  mvyx[k] = mm;  float dvy_x = d + mm;
            d = (FC1 * (sV[1][vi + VS] - sV[1][vi]) + FC2 * (sV[1][vi + 2 * VS] - sV[1][vi - VS])) * INV_DX;
            mm = by_ * mvxy[k] + ay_ * d;  mvxy[k] = mm;  float dvx_y = d + mm;
            float nsxy = sS[1][si] + DTF * mu_t[k] * (dvy_x + dvx_y);
            sS[0][si] = nsyy; sS[1][si] = nsxy; sS[2][si] = nsxx;
            if (pub && ((ringm >> k) & 1)) {
                int gi = gidx_t[k];
                cohstore(&gsw[(0 * NS + shot) * NCELL + gi], nsyy);
                cohstore(&gsw[(1 * NS + shot) * NCELL + gi], nsxy);
                cohstore(&gsw[(2 * NS + shot) * NCELL + gi], nsxx);
            }
        }
    };

    // ========== time loop: neighbor-flag sync only (no global barrier) ==========
    // flag[b] = #steps b has published. Skew between neighbors <= 1 step, so the
    // parity double-buffer separates readers/writers.
    // Per-step chain: [vel-int | poll] B1 [frame loads issued; stress-int overlaps
    // the load latency; frame->LDS] B2 [vel-bnd] B3 [recv; stress-ring+publish] B4 [flag].
    // SAFETY of early stress on [4..32]^2: boundary vel reads stress(t-1) only at
    // rows/cols in [-4..2] U [34..40] (stencil verified) -- disjoint from [4..32].
    for (int t = 0; t < NT; ++t) {
        const float* gsr = gstr + ((t + 1) & 1) * GSLOT;   // neighbors' state(t-1)
        float*       gsw = gstr + (t & 1) * GSLOT;         // my state(t)

        // interior velocity: no frame dependency -> overlaps neighbor drift
        do_vel(intm, t);

        // wait: my 8 neighbors must have published ring(t-1)
        if (t > 0 && myNbr >= 0) {
            while (__hip_atomic_load(&flags[myNbr], __ATOMIC_RELAXED,
                                     __HIP_MEMORY_SCOPE_AGENT) < t)
                __builtin_amdgcn_s_sleep(1);
        }
        __syncthreads();   // B1: poll done + interior vel visible

        // issue frame loads (results consumed after interior stress -> latency hidden)
        float fr0[3], fr1[3];
        #pragma unroll
        for (int f = 0; f < 3; ++f) {
            fr0[f] = (t > 0 && fin[0]) ? cohload(&gsr[(f * NS + shot) * NCELL + fgi[0]]) : 0.0f;
            fr1[f] = (t > 0 && fin[1]) ? cohload(&gsr[(f * NS + shot) * NCELL + fgi[1]]) : 0.0f;
        }

        // interior stress (cells [4..32]^2) overlaps the frame-load latency
        do_stress(ctm & ~ringm, false, gsw);

        // frame -> LDS (the vmcnt wait lands here, after the stress work above)
        if (fval[0]) { sS[0][flidx[0]] = fr0[0]; sS[1][flidx[0]] = fr0[1]; sS[2][flidx[0]] = fr0[2]; }
        if (fval[1]) { sS[0][flidx[1]] = fr1[0]; sS[1][flidx[1]] = fr1[1]; sS[2][flidx[1]] = fr1[2]; }
        __syncthreads();   // B2: frame + interior stress visible

        // boundary velocity (needs frame)
        do_vel(bndm, t);
        __syncthreads();   // B3: all vel(t) visible

        // receivers: vy after injection (LDS-resident)
        if (tid < rcnt)
            out[(shot * NREC + rl_r[tid]) * NT + t] = sV[0][rl_pos[tid]];

        // ring stress; ring cells published immediately (same thread owns both)
        do_stress(ringm, true, gsw);

        // publish: syncthreads drains all waves' ring stores (vmcnt(0)) -> flag store
        __syncthreads();   // B4
        if (tid == 0 && t < NT - 1)
            __hip_atomic_store(&flags[myBlk], t + 1, __ATOMIC_RELAXED,
                               __HIP_MEMORY_SCOPE_AGENT);
    }
}

extern "C" void kernel_launch(void* const* d_in, const int* in_sizes, int n_in,
                              void* d_out, int out_size, void* d_ws, size_t ws_size,
                              hipStream_t stream) {
    const float* lamb    = (const float*)d_in[0];
    const float* mu      = (const float*)d_in[1];
    const float* buoy    = (const float*)d_in[2];
    const float* amps    = (const float*)d_in[3];
    const int*   src_loc = (const int*)d_in[4];
    const int*   rec_loc = (const int*)d_in[5];
    float* ws  = (float*)d_ws;
    float* out = (float*)d_out;

    // No memset needed: flags/vmax-slots are poison-tolerant (see ws layout comment).
    elastic_fused<<<NBLK, NTHR, 0, stream>>>(lamb, mu, buoy, amps, src_loc, rec_loc, out, ws);
}